// Round 1
// 124.503 us; speedup vs baseline: 1.0427x; 1.0427x over previous
//
#include <hip/hip_runtime.h>
#include <math.h>

#define BATCH 8
#define SEQ   4096
#define DM    128
#define DS    128
#define N2    4096   // complex FFT length (r2c half-size; conv length 8192)
#define NT    256
#define NTP   256

__device__ __forceinline__ float2 cmulf(float2 a, float2 b) {
    return make_float2(a.x * b.x - a.y * b.y, a.x * b.y + a.y * b.x);
}
__device__ __forceinline__ float2 caddf(float2 a, float2 b) { return make_float2(a.x + b.x, a.y + b.y); }
__device__ __forceinline__ float2 csubf(float2 a, float2 b) { return make_float2(a.x - b.x, a.y - b.y); }
__device__ __forceinline__ float2 conjf2(float2 a) { return make_float2(a.x, -a.y); }
__device__ __forceinline__ float2 cisf(float t) { float s, c; __sincosf(t, &s, &c); return make_float2(c, s); }

// nibble-reverse of 12-bit index (involution): bin k sits at logical position nibrev(k)
__device__ __forceinline__ int nibrev(int k) { return ((k & 15) << 8) | (k & 0xF0) | (k >> 8); }
// LDS anti-conflict swizzle (involutive bijection)
__device__ __forceinline__ int physi(int a) { return a ^ ((a >> 4) & 15); }
// PQ table slot for logical position pos (transposed so conv reads coalesced)
__device__ __forceinline__ int pqslot(int p) { return ((p & 15) << 8) | (p >> 4); }

// ---------------- in-register DFT-16 (verified R4) ----------------
__device__ __forceinline__ void dft16_fwd_l2(const float2 y[16], float2 Xh[16]) {
#pragma unroll
    for (int g = 0; g < 4; ++g) {
        float2 a0 = y[4*g], a1 = y[4*g+1], a2 = y[4*g+2], a3 = y[4*g+3];
        float2 t0 = caddf(a0,a2), t1 = csubf(a0,a2);
        float2 t2 = caddf(a1,a3), t3 = csubf(a1,a3);
        Xh[4*g]   = caddf(t0,t2);
        Xh[4*g+1] = make_float2(t1.x + t3.y, t1.y - t3.x);
        Xh[4*g+2] = csubf(t0,t2);
        Xh[4*g+3] = make_float2(t1.x - t3.y, t1.y + t3.x);
    }
}
__device__ __forceinline__ void dft16_inv_l2(const float2 y[16], float2 Xh[16]) {
#pragma unroll
    for (int g = 0; g < 4; ++g) {
        float2 a0 = y[4*g], a1 = y[4*g+1], a2 = y[4*g+2], a3 = y[4*g+3];
        float2 t0 = caddf(a0,a2), t1 = csubf(a0,a2);
        float2 t2 = caddf(a1,a3), t3 = csubf(a1,a3);
        Xh[4*g]   = caddf(t0,t2);
        Xh[4*g+1] = make_float2(t1.x - t3.y, t1.y + t3.x);
        Xh[4*g+2] = csubf(t0,t2);
        Xh[4*g+3] = make_float2(t1.x + t3.y, t1.y - t3.x);
    }
}

__device__ __forceinline__ void dft16_fwd(const float2 x[16], float2 Xh[16]) {
    const float2 W[10] = { {1.f,0.f},
        {0.92387953f,-0.38268343f},{0.70710678f,-0.70710678f},{0.38268343f,-0.92387953f},
        {0.f,-1.f},{-0.38268343f,-0.92387953f},{-0.70710678f,-0.70710678f},
        {-0.92387953f,-0.38268343f},{-1.f,0.f},{-0.92387953f,0.38268343f} };
    float2 y[16];
#pragma unroll
    for (int j = 0; j < 4; ++j) {
        float2 a0 = x[j], a1 = x[j+4], a2 = x[j+8], a3 = x[j+12];
        float2 t0 = caddf(a0,a2), t1 = csubf(a0,a2);
        float2 t2 = caddf(a1,a3), t3 = csubf(a1,a3);
        float2 b1 = make_float2(t1.x + t3.y, t1.y - t3.x);
        float2 b3 = make_float2(t1.x - t3.y, t1.y + t3.x);
        y[j]    = caddf(t0,t2);
        y[j+4]  = cmulf(b1, W[j]);
        y[j+8]  = cmulf(csubf(t0,t2), W[2*j]);
        y[j+12] = cmulf(b3, W[3*j]);
    }
    dft16_fwd_l2(y, Xh);
}

// forward DFT-16 with x[8..15] structurally zero (zero-padded conv input)
__device__ __forceinline__ void dft16_fwd_zh(const float2 x[8], float2 Xh[16]) {
    const float2 W[10] = { {1.f,0.f},
        {0.92387953f,-0.38268343f},{0.70710678f,-0.70710678f},{0.38268343f,-0.92387953f},
        {0.f,-1.f},{-0.38268343f,-0.92387953f},{-0.70710678f,-0.70710678f},
        {-0.92387953f,-0.38268343f},{-1.f,0.f},{-0.92387953f,0.38268343f} };
    float2 y[16];
#pragma unroll
    for (int j = 0; j < 4; ++j) {
        float2 a0 = x[j], a1 = x[j+4];
        // a2=a3=0 -> t0=t1=a0, t2=t3=a1
        float2 b1 = make_float2(a0.x + a1.y, a0.y - a1.x);
        float2 b3 = make_float2(a0.x - a1.y, a0.y + a1.x);
        y[j]    = caddf(a0, a1);
        y[j+4]  = cmulf(b1, W[j]);
        y[j+8]  = cmulf(csubf(a0, a1), W[2*j]);
        y[j+12] = cmulf(b3, W[3*j]);
    }
    dft16_fwd_l2(y, Xh);
}

__device__ __forceinline__ void dft16_inv(const float2 x[16], float2 Xh[16]) {
    const float2 W[10] = { {1.f,0.f},
        {0.92387953f,0.38268343f},{0.70710678f,0.70710678f},{0.38268343f,0.92387953f},
        {0.f,1.f},{-0.38268343f,0.92387953f},{-0.70710678f,0.70710678f},
        {-0.92387953f,0.38268343f},{-1.f,0.f},{-0.92387953f,-0.38268343f} };
    float2 y[16];
#pragma unroll
    for (int j = 0; j < 4; ++j) {
        float2 a0 = x[j], a1 = x[j+4], a2 = x[j+8], a3 = x[j+12];
        float2 t0 = caddf(a0,a2), t1 = csubf(a0,a2);
        float2 t2 = caddf(a1,a3), t3 = csubf(a1,a3);
        float2 b1 = make_float2(t1.x - t3.y, t1.y + t3.x);
        float2 b3 = make_float2(t1.x + t3.y, t1.y - t3.x);
        y[j]    = caddf(t0,t2);
        y[j+4]  = cmulf(b1, W[j]);
        y[j+8]  = cmulf(csubf(t0,t2), W[2*j]);
        y[j+12] = cmulf(b3, W[3*j]);
    }
    dft16_inv_l2(y, Xh);
}

// inverse DFT-16 producing only outputs Xh[sr(r)], r<8 (out8[r] = Xh[((r&3)<<2)|(r>>2)])
__device__ __forceinline__ void dft16_inv_lo8(const float2 x[16], float2 out8[8]) {
    const float2 W[10] = { {1.f,0.f},
        {0.92387953f,0.38268343f},{0.70710678f,0.70710678f},{0.38268343f,0.92387953f},
        {0.f,1.f},{-0.38268343f,0.92387953f},{-0.70710678f,0.70710678f},
        {-0.92387953f,0.38268343f},{-1.f,0.f},{-0.92387953f,-0.38268343f} };
    float2 y[16];
#pragma unroll
    for (int j = 0; j < 4; ++j) {
        float2 a0 = x[j], a1 = x[j+4], a2 = x[j+8], a3 = x[j+12];
        float2 t0 = caddf(a0,a2), t1 = csubf(a0,a2);
        float2 t2 = caddf(a1,a3), t3 = csubf(a1,a3);
        float2 b1 = make_float2(t1.x - t3.y, t1.y + t3.x);
        float2 b3 = make_float2(t1.x + t3.y, t1.y - t3.x);
        y[j]    = caddf(t0,t2);
        y[j+4]  = cmulf(b1, W[j]);
        y[j+8]  = cmulf(csubf(t0,t2), W[2*j]);
        y[j+12] = cmulf(b3, W[3*j]);
    }
#pragma unroll
    for (int g = 0; g < 4; ++g) {
        float2 a0 = y[4*g], a1 = y[4*g+1], a2 = y[4*g+2], a3 = y[4*g+3];
        float2 t0 = caddf(a0,a2), t1 = csubf(a0,a2);
        float2 t2 = caddf(a1,a3), t3 = csubf(a1,a3);
        out8[g]   = caddf(t0,t2);                              // Xh[4g]
        out8[4+g] = make_float2(t1.x - t3.y, t1.y + t3.x);     // Xh[4g+1]
    }
}

// ---------------- radix-16 LDS stages ----------------
// Q=16 forward stage; twiddle chain split into two 8-deep chains (latency/2)
__device__ __forceinline__ void stage16_fwd(float2* z, int t) {
    float2 x[16], Xh[16];
    int adr[16];
    int j = t & 15, top = t >> 4;
#pragma unroll
    for (int r = 0; r < 16; ++r) adr[r] = (top << 8) + (r << 4) + (j ^ r);
#pragma unroll
    for (int r = 0; r < 16; ++r) x[r] = z[adr[r]];
    dft16_fwd(x, Xh);
    float ang = -(float)M_PI / 128.0f * (float)j;
    float2 w1 = cisf(ang);
    float2 wa = make_float2(1.f, 0.f);
    float2 wb = cisf(ang * 8.0f);
#pragma unroll
    for (int k = 0; k < 8; ++k) {
        int sk = ((k & 3) << 2) | (k >> 2);
        z[adr[k]]     = cmulf(Xh[sk],     wa);
        z[adr[k + 8]] = cmulf(Xh[sk + 2], wb);
        wa = cmulf(wa, w1);
        wb = cmulf(wb, w1);
    }
}

// Q=16 inverse stage; same chain split on input twiddles
__device__ __forceinline__ void stage16_inv(float2* z, int t) {
    float2 x[16], Xh[16];
    int adr[16];
    int j = t & 15, top = t >> 4;
#pragma unroll
    for (int r = 0; r < 16; ++r) adr[r] = (top << 8) + (r << 4) + (j ^ r);
    float ang = (float)M_PI / 128.0f * (float)j;
    float2 w1 = cisf(ang);
    float2 wa = make_float2(1.f, 0.f);
    float2 wb = cisf(ang * 8.0f);
#pragma unroll
    for (int k = 0; k < 8; ++k) {
        x[k]     = cmulf(z[adr[k]],     wa);
        x[k + 8] = cmulf(z[adr[k + 8]], wb);
        wa = cmulf(wa, w1);
        wb = cmulf(wb, w1);
    }
    dft16_inv(x, Xh);
#pragma unroll
    for (int r = 0; r < 16; ++r) {
        int sr = ((r & 3) << 2) | (r >> 2);
        z[adr[r]] = Xh[sr];
    }
}

// Q=1 forward stage that also KEEPS its outputs in registers:
// v[k] = value written to z[physi((t<<4)|k)], i.e. V[pos=(t<<4)|k]
__device__ __forceinline__ void stage1_fwd_keep(float2* z, int t, float2 v[16]) {
    float2 x[16], Xh[16];
    int adr[16];
    int j4 = t & 15;
#pragma unroll
    for (int r = 0; r < 16; ++r) adr[r] = (t << 4) + (j4 ^ r);
#pragma unroll
    for (int r = 0; r < 16; ++r) x[r] = z[adr[r]];
    dft16_fwd(x, Xh);
#pragma unroll
    for (int k = 0; k < 16; ++k) {
        int sk = ((k & 3) << 2) | (k >> 2);
        v[k] = Xh[sk];
        z[adr[k]] = v[k];
    }
}

// first forward stage from global (upper half zero), split twiddle chains
__device__ __forceinline__ void fwd_first(float2* z, const float2* __restrict__ vrow, int t) {
    float2 x8[8], Xh[16];
#pragma unroll
    for (int r = 0; r < 8; ++r) x8[r] = vrow[t + (r << 8)];
    dft16_fwd_zh(x8, Xh);
    int b0 = t ^ ((t >> 4) & 15);
    float ang = -(float)M_PI / 2048.0f * (float)t;
    float2 w1 = cisf(ang);
    float2 wa = make_float2(1.f, 0.f);
    float2 wb = cisf(ang * 8.0f);
#pragma unroll
    for (int k = 0; k < 8; ++k) {
        int sk = ((k & 3) << 2) | (k >> 2);
        z[b0 + (k << 8)]       = cmulf(Xh[sk],     wa);
        z[b0 + ((k + 8) << 8)] = cmulf(Xh[sk + 2], wb);
        wa = cmulf(wa, w1);
        wb = cmulf(wb, w1);
    }
}

__device__ __forceinline__ void inv_last_store(const float2* z, float2* __restrict__ xrow,
                                               int t, float dv) {
    float2 x[16], out8[8];
    int b0 = t ^ ((t >> 4) & 15);
    float ang = (float)M_PI / 2048.0f * (float)t;
    float2 w1 = cisf(ang);
    float2 wa = make_float2(1.f, 0.f);
    float2 wb = cisf(ang * 8.0f);
#pragma unroll
    for (int k = 0; k < 8; ++k) {
        x[k]     = cmulf(z[b0 + (k << 8)],       wa);
        x[k + 8] = cmulf(z[b0 + ((k + 8) << 8)], wb);
        wa = cmulf(wa, w1);
        wb = cmulf(wb, w1);
    }
    dft16_inv_lo8(x, out8);
    const float invN = 1.0f / 4096.0f;
#pragma unroll
    for (int r = 0; r < 8; ++r) {
        float2 res = out8[r];
        float2 xv = xrow[t + (r << 8)];
        xrow[t + (r << 8)] = make_float2(res.x * invN + dv * xv.x, res.y * invN + dv * xv.y);
    }
}

// ---------------- P/Q pair coefficients; e = cisf(-thk) passed in (1 sincos/pair) ----------------
__device__ __forceinline__ void pq_one_e(float2 Kk, float2 Kkp, float2 e,
                                         float2 fap, float2 fbp,
                                         float2* P, float2* Q) {
    float2 fa = make_float2(0.5f * (1.f + e.y), -0.5f * e.x);
    float2 fb = make_float2(0.5f * (1.f - e.y),  0.5f * e.x);
    float2 ak = cmulf(Kk, fa), bk = cmulf(Kk, fb);
    float2 apv = cmulf(Kkp, fap), bpv = cmulf(Kkp, fbp);
    float2 g = make_float2(0.5f * (1.f + e.y), 0.5f * e.x);
    float2 h = make_float2(0.5f * (1.f - e.y), -0.5f * e.x);
    *P = caddf(cmulf(g, ak), cmulf(h, conjf2(bpv)));
    *Q = caddf(cmulf(g, bk), cmulf(h, conjf2(apv)));
}
// thkp = pi - thk  =>  cisf(-thkp) = (-e.x, e.y) exactly
__device__ __forceinline__ void pq_pair_e(float2 Kk, float2 Kkp, float2 e,
                                          float2* Pk, float2* Qk, float2* Pkp, float2* Qkp) {
    float2 ep = make_float2(-e.x, e.y);
    float2 fa  = make_float2(0.5f * (1.f + e.y),  -0.5f * e.x);
    float2 fb  = make_float2(0.5f * (1.f - e.y),   0.5f * e.x);
    float2 fap = make_float2(0.5f * (1.f + ep.y), -0.5f * ep.x);
    float2 fbp = make_float2(0.5f * (1.f - ep.y),  0.5f * ep.x);
    pq_one_e(Kk,  Kkp, e,  fap, fbp, Pk,  Qk);
    pq_one_e(Kkp, Kk,  ep, fa,  fb,  Pkp, Qkp);
}

// ---------------- fused prep: psum (0..255) || G (256..319) || transpose_xin (320..4415) --------
__global__ void __launch_bounds__(NTP) prep_fused(
    const float* __restrict__ Lam, const float* __restrict__ logdt, float* __restrict__ Psum,
    const float* __restrict__ Cm, const float* __restrict__ Bm, float* __restrict__ GT,
    const float* __restrict__ x, float* __restrict__ xt) {
    __shared__ float E[DM];
    __shared__ float tile[32][33];
    int bid = blockIdx.x, t = threadIdx.x;
    if (bid < 256) {
        int s = bid >> 1, half = bid & 1;
        if (t < DM) E[t] = __expf(logdt[t]) * Lam[s];
        __syncthreads();
        int l0 = t + 2048 * half;
        float acc[8] = {0.f,0.f,0.f,0.f,0.f,0.f,0.f,0.f};
        for (int m = 0; m < DM; ++m) {
            float e = E[m];
            float w = __expf(e * (float)l0);
            float r = __expf(e * 256.0f);
#pragma unroll
            for (int i = 0; i < 8; ++i) { acc[i] += w; w *= r; }
        }
#pragma unroll
        for (int i = 0; i < 8; ++i) Psum[s * SEQ + l0 + 256 * i] = acc[i];
    } else if (bid < 320) {
        int gid = (bid - 256) * NTP + t;
        int m = gid >> 7, j = gid & 127;
        float acc = 0.f;
        for (int i = 0; i < DS; ++i) acc += Cm[m * DS + i] * Bm[i * DM + j];
        GT[j * DM + m] = acc;   // transposed for prep_K2
    } else {
        int u = bid - 320;
        int b = u >> 9;
        int m0 = ((u >> 7) & 3) * 32;
        int l0 = (u & 127) * 32;
        int lr = t >> 3, mc4 = (t & 7) * 4;
        float4 v = *(const float4*)&x[(size_t)b * SEQ * DM + (size_t)(l0 + lr) * DM + m0 + mc4];
        tile[lr][mc4 + 0] = v.x; tile[lr][mc4 + 1] = v.y;
        tile[lr][mc4 + 2] = v.z; tile[lr][mc4 + 3] = v.w;
        __syncthreads();
        int mr = t >> 3, lc4 = (t & 7) * 4;
        float4 o = make_float4(tile[lc4 + 0][mr], tile[lc4 + 1][mr],
                               tile[lc4 + 2][mr], tile[lc4 + 3][mr]);
        *(float4*)&xt[(size_t)b * DM * SEQ + (size_t)(m0 + mr) * SEQ + l0 + lc4] = o;
    }
}

// K[m,l] = sum_s GT[s,m]*Psum[s,l] (verified R4)
__global__ void prep_K2(const float* __restrict__ GT, const float* __restrict__ Psum,
                        float* __restrict__ K) {
    __shared__ float4 PT[DS][4];
    int l0 = blockIdx.x * 16;
    int t = threadIdx.x;
    for (int idx = t; idx < 512; idx += NTP) {
        int s = idx >> 2, q = idx & 3;
        PT[s][q] = ((const float4*)(Psum + s * SEQ + l0))[q];
    }
    __syncthreads();
    int m = t & 127, half = t >> 7;
    float acc[8] = {0.f,0.f,0.f,0.f,0.f,0.f,0.f,0.f};
    for (int s = 0; s < DS; ++s) {
        float g = GT[s * DM + m];
        float4 p0 = PT[s][half * 2], p1 = PT[s][half * 2 + 1];
        acc[0] += g * p0.x; acc[1] += g * p0.y; acc[2] += g * p0.z; acc[3] += g * p0.w;
        acc[4] += g * p1.x; acc[5] += g * p1.y; acc[6] += g * p1.z; acc[7] += g * p1.w;
    }
    float4* kp = (float4*)(K + (size_t)m * SEQ + l0 + half * 8);
    kp[0] = make_float4(acc[0], acc[1], acc[2], acc[3]);
    kp[1] = make_float4(acc[4], acc[5], acc[6], acc[7]);
}

// ---------------- fftK_PQ epilogue over c = C0..C0+3 (each pair handled once: bit3(pos)==0) ----
template<int C0>
__device__ __forceinline__ void pq_epilogue(const float2 v[16], const float2* z,
                                            float4* __restrict__ dst, int t) {
#pragma unroll
    for (int cc = 0; cc < 4; ++cc) {
        const int c = C0 + cc;
        int pos = (t << 4) | c;
        float2 Pk, Qk, Pkp, Qkp;
        if (pos == 0) {
            float2 v0 = v[0];
            float2 v2 = v[8];
            float2 Ku0    = make_float2(v0.x + v0.y, 0.f);
            float2 Ku4096 = make_float2(v0.x - v0.y, 0.f);
            float2 Ku2048 = conjf2(v2);
            float2 Pd, Qd;
            pq_pair_e(Ku0, Ku4096, make_float2(1.f, 0.f), &Pk, &Qk, &Pd, &Qd);
            float2 Pd2, Qd2;
            pq_pair_e(Ku2048, Ku2048, make_float2(0.f, -1.f), &Pkp, &Qkp, &Pd2, &Qd2);
            dst[pqslot(0)] = make_float4(Pk.x, Pk.y, Qk.x, Qk.y);     // pos 0 (self-pair)
            dst[pqslot(8)] = make_float4(Pkp.x, Pkp.y, Qkp.x, Qkp.y); // pos 8 (self-pair)
        } else {
            int k  = nibrev(pos);
            int kp = 4096 - k;
            int ppos = nibrev(kp);
            float2 va = v[c];                   // own stage-1 output, kept in registers
            float2 vb = z[physi(ppos)];
            float thk = (float)M_PI * (float)k / 4096.0f;
            float2 e  = cisf(-thk);             // the ONLY sincos for this pair
            float2 cb = conjf2(vb);
            float2 s  = caddf(va, cb), d = csubf(va, cb);
            float2 pr = cmulf(e, d);
            float2 Kuk = make_float2(0.5f * (s.x + pr.y), 0.5f * (s.y - pr.x));
            float2 ep = make_float2(-e.x, e.y);
            float2 ca = conjf2(va);
            float2 s2 = caddf(vb, ca), d2 = csubf(vb, ca);
            float2 p2 = cmulf(ep, d2);
            float2 Kukp = make_float2(0.5f * (s2.x + p2.y), 0.5f * (s2.y - p2.x));
            pq_pair_e(Kuk, Kukp, e, &Pk, &Qk, &Pkp, &Qkp);
            dst[pqslot(pos)]  = make_float4(Pk.x, Pk.y, Qk.x, Qk.y);     // coalesced: (c<<8)|t
            dst[pqslot(ppos)] = make_float4(Pkp.x, Pkp.y, Qkp.x, Qkp.y); // scattered
        }
    }
}

// 256 blocks: 2 blocks per m (redundant FFT on otherwise-idle CUs), half the epilogue each
__global__ void __launch_bounds__(NT, 4) fftK_PQ(const float* __restrict__ K,
                                                 float4* __restrict__ PQ) {
    __shared__ __align__(16) float2 z[N2];
    int t = threadIdx.x;
    int m = blockIdx.x & (DM - 1);
    int half = blockIdx.x >> 7;
    const float2* krow = (const float2*)(K + (size_t)m * SEQ);

    fwd_first(z, krow, t);  __syncthreads();
    stage16_fwd(z, t);      __syncthreads();
    float2 v[16];
    stage1_fwd_keep(z, t, v); __syncthreads();

    float4* dst = PQ + (size_t)m * 4096;
    if (half == 0) pq_epilogue<0>(v, z, dst, t);
    else           pq_epilogue<4>(v, z, dst, t);
}

// ---------------- main convolution: pointwise fused into inverse Q=1 stage ----------------
__global__ void __launch_bounds__(NT, 4) conv16(float* __restrict__ xt,
                                                const float4* __restrict__ PQ,
                                                const float* __restrict__ Dv) {
    __shared__ __align__(16) float2 z[N2];
    int t = threadIdx.x;
    int m = blockIdx.x & (DM - 1);
    int b = blockIdx.x >> 7;
    float2* xrow = (float2*)(xt + (((size_t)b * DM + m) << 12));

    fwd_first(z, xrow, t);  __syncthreads();
    stage16_fwd(z, t);      __syncthreads();
    float2 v[16];
    stage1_fwd_keep(z, t, v); __syncthreads();   // v[r] == V[(t<<4)|r]; z holds all V for partners

    // fused pointwise: own V already in registers; only partner V read from LDS.
    {
        const float4* pq = PQ + (size_t)m * 4096;
#pragma unroll
        for (int r = 0; r < 16; ++r) {
            int pos = (t << 4) | r;
            int k  = nibrev(pos);
            int kp = (4096 - k) & 4095;
            float2 vb = z[physi(nibrev(kp))];            // partner (self for pos 0,8)
            float4 co = pq[(r << 8) | t];                // coalesced per r
            v[r] = caddf(cmulf(make_float2(co.x, co.y), v[r]),
                         cmulf(make_float2(co.z, co.w), conjf2(vb)));
        }
    }
    __syncthreads();   // all partner reads done before any write below
    {
        float2 Xh[16];
        dft16_inv(v, Xh);
        int j4 = t & 15;
#pragma unroll
        for (int r = 0; r < 16; ++r) {
            int sr = ((r & 3) << 2) | (r >> 2);
            z[(t << 4) + (r ^ j4)] = Xh[sr];
        }
    }
    __syncthreads();

    stage16_inv(z, t);      __syncthreads();
    inv_last_store(z, xrow, t, Dv[m]);
}

// ---------------- float4 transpose out (R7 verbatim) ----------------
__global__ void transpose_yout(const float* __restrict__ yt, float* __restrict__ out) {
    __shared__ float tile[32][33];
    int b = blockIdx.z;
    int l0 = blockIdx.x * 32, m0 = blockIdx.y * 32;
    int t = threadIdx.x;
    int mr = t >> 3, lc4 = (t & 7) * 4;
    float4 v = *(const float4*)&yt[(size_t)b * DM * SEQ + (size_t)(m0 + mr) * SEQ + l0 + lc4];
    tile[mr][lc4 + 0] = v.x; tile[mr][lc4 + 1] = v.y;
    tile[mr][lc4 + 2] = v.z; tile[mr][lc4 + 3] = v.w;
    __syncthreads();
    int lr = t >> 3, mc4 = (t & 7) * 4;
    float4 o = make_float4(tile[mc4 + 0][lr], tile[mc4 + 1][lr],
                           tile[mc4 + 2][lr], tile[mc4 + 3][lr]);
    *(float4*)&out[(size_t)b * SEQ * DM + (size_t)(l0 + lr) * DM + m0 + mc4] = o;
}

extern "C" void kernel_launch(void* const* d_in, const int* in_sizes, int n_in,
                              void* d_out, int out_size, void* d_ws, size_t ws_size,
                              hipStream_t stream) {
    const float* x     = (const float*)d_in[0];
    const float* Lam   = (const float*)d_in[1];
    const float* Bm    = (const float*)d_in[2];
    const float* Cm    = (const float*)d_in[3];
    const float* Dv    = (const float*)d_in[4];
    const float* logdt = (const float*)d_in[5];
    float* out = (float*)d_out;

    float*  ws   = (float*)d_ws;
    float*  xt   = ws;                                   // 4,194,304 floats (16 MB)
    float4* PQ   = (float4*)(ws + 4194304);              // 128*4096 float4 (8 MB)
    float*  K    = ws + 4194304 + 2097152;               // 524,288 floats (2 MB)
    float*  Psum = K + 524288;                           // 524,288 floats (2 MB)
    float*  GT   = Psum + 524288;                        // 16,384 floats

    hipLaunchKernelGGL(prep_fused,     dim3(4416),       dim3(NTP),  0, stream,
                       Lam, logdt, Psum, Cm, Bm, GT, x, xt);
    hipLaunchKernelGGL(prep_K2,        dim3(256),        dim3(NTP),  0, stream, GT, Psum, K);
    hipLaunchKernelGGL(fftK_PQ,        dim3(256),        dim3(NT),   0, stream, K, PQ);
    hipLaunchKernelGGL(conv16,         dim3(1024),       dim3(NT),   0, stream, xt, PQ, Dv);
    hipLaunchKernelGGL(transpose_yout, dim3(128, 4, 8),  dim3(NT),   0, stream, xt, out);
}